// Round 2
// baseline (266.436 us; speedup 1.0000x reference)
//
#include <hip/hip_runtime.h>

typedef __bf16 bf16;
typedef __bf16 bf16x8 __attribute__((ext_vector_type(8)));
typedef float f32x4 __attribute__((ext_vector_type(4)));

#define DEV __device__ __forceinline__
#define NEG_BIG (-1.0e30f)

// B=2, T=2048, C=1024, H=16, D=64; M = B*T = 4096

DEV bf16x8 load8(const bf16* p) { bf16x8 v; __builtin_memcpy(&v, p, 16); return v; }
DEV void store8(bf16* p, bf16x8 v) { __builtin_memcpy(p, &v, 16); }

// ---------------- in-kernel dtype sniff (block-uniform, deterministic) ----------------
DEV int sniff_bf16(const unsigned short* __restrict__ xr) {
  const int lane = threadIdx.x & 63;
  const unsigned short w = xr[lane * 2];
  const int e = (w >> 7) & 0xFF;
  const bool sane = ((w & 0x7FFF) == 0) || (e >= 97 && e <= 157);
  return __popcll(__ballot(sane)) >= 48;
}

// ---------------- input canonicalization (-> bf16, row-major) ----------------
struct ConvArgs {
  const void* src[6];
  bf16* dst[6];
  int n[6];
};

__global__ __launch_bounds__(256) void convert_kernel(ConvArgs a) {
  const int isbf = sniff_bf16((const unsigned short*)a.src[0]);
  const int t = blockIdx.y;
  const int n = a.n[t];
  bf16* d = a.dst[t];
  const int stride = gridDim.x * 256 * 8;
  if (isbf) {
    const bf16* s = (const bf16*)a.src[t];
    for (int i = (blockIdx.x * 256 + threadIdx.x) * 8; i < n; i += stride)
      store8(d + i, load8(s + i));
  } else {
    const float* s = (const float*)a.src[t];
    for (int i = (blockIdx.x * 256 + threadIdx.x) * 8; i < n; i += stride) {
      float tmp[8];
      __builtin_memcpy(tmp, s + i, 32);
      bf16x8 v;
#pragma unroll
      for (int j = 0; j < 8; ++j) v[j] = (bf16)tmp[j];
      store8(d + i, v);
    }
  }
}

// ---------------- GEMM core: barrier-free, LDS-free, per-wave 64x64 tile ----------------
// One wave owns C[m0:m0+64, n0:n0+64] = A[m0:,:K] * W[n0:,:K]^T.
// Fragment loads go straight global->VGPR: lane (lr,lg) loads 16B at
// row (i*16+lr), k = h*32 + lg*8 -- 16 fully-consumed 64B lines per
// instruction, k-offset folds into the 13-bit immediate (h*64 <= 1984).
// Static 2-set ping-pong (full unroll => compile-time indices, no scratch);
// one half-step of loads stays in flight under the current 16 MFMAs, and
// cross-wave TLP (3 waves/SIMD) covers the rest. No __syncthreads anywhere.
DEV void gemm_wave64(const bf16* __restrict__ A, const bf16* __restrict__ W,
                     const int K, int m0, int n0, f32x4 (&acc)[4][4]) {
  const int lane = threadIdx.x & 63;
  const int lr = lane & 15, lg = lane >> 4;

  const bf16* pa[4];
  const bf16* pb[4];
#pragma unroll
  for (int i = 0; i < 4; ++i) pa[i] = A + (size_t)(m0 + i * 16 + lr) * K + lg * 8;
#pragma unroll
  for (int j = 0; j < 4; ++j) pb[j] = W + (size_t)(n0 + j * 16 + lr) * K + lg * 8;

  const f32x4 zero = {0.f, 0.f, 0.f, 0.f};
#pragma unroll
  for (int i = 0; i < 4; ++i)
#pragma unroll
    for (int j = 0; j < 4; ++j) acc[i][j] = zero;

  bf16x8 aA[4], bA[4], aB[4], bB[4];

  auto loadset = [&](int h, bf16x8 (&af)[4], bf16x8 (&bf)[4]) {
#pragma unroll
    for (int i = 0; i < 4; ++i) af[i] = load8(pa[i] + h * 32);
#pragma unroll
    for (int j = 0; j < 4; ++j) bf[j] = load8(pb[j] + h * 32);
  };
  auto mm = [&](const bf16x8 (&af)[4], const bf16x8 (&bf)[4]) {
#pragma unroll
    for (int i = 0; i < 4; ++i)
#pragma unroll
      for (int j = 0; j < 4; ++j)
        acc[i][j] = __builtin_amdgcn_mfma_f32_16x16x32_bf16(af[i], bf[j], acc[i][j], 0, 0, 0);
  };

  // 32 half-steps of k (K=1024, 32 elems each), 2-set software pipeline.
  loadset(0, aA, bA);
  loadset(1, aB, bB);
#pragma unroll
  for (int h = 0; h < 32; ++h) {
    if ((h & 1) == 0) {
      mm(aA, bA);
      if (h + 2 < 32) loadset(h + 2, aA, bA);
    } else {
      mm(aB, bB);
      if (h + 2 < 32) loadset(h + 2, aB, bB);
    }
  }
}

// Fragment-order address for a 64x64 tile, element (row, col):
//   chunk = ((col>>5)*4 + ((row>>4)&3))*64 + ((col>>3)&3)*16 + (row&15), elem = col&7
// Q/K use (row=t-in-tile, col=d); V^T uses (row=d, col=t-in-tile).
DEV size_t frag_idx(int row, int col) {
  return ((size_t)(((col >> 5) * 4 + ((row >> 4) & 3)) * 64 + ((col >> 3) & 3) * 16 + (row & 15)) << 3)
         | (size_t)(col & 7);
}

// 1-D grid 3072 single-wave blocks. xcd = L&7; per-XCD: i&7 = m-tile (8 tiles,
// 512 rows -> 1 MiB x-slice stays L2-resident), i>>3 = (n0, mode) 0..47 --
// consecutive blocks share the W-slice, so it is L2-hot while in use.
__global__ __launch_bounds__(64) void qkv_proj_kernel(
    const bf16* __restrict__ x, const bf16* __restrict__ Wq,
    const bf16* __restrict__ Wk, const bf16* __restrict__ Wv,
    bf16* __restrict__ q_ws, bf16* __restrict__ k_ws, bf16* __restrict__ vt_ws) {
  const int L = blockIdx.x;
  const int xcd = L & 7;
  const int i2 = L >> 3;                 // 0..383
  const int m0 = (xcd * 8 + (i2 & 7)) << 6;
  const int rest = i2 >> 3;              // 0..47
  const int n0 = (rest & 15) << 6;
  const int mode = rest >> 4;            // 0..2
  const bf16* W = (mode == 0) ? Wq : (mode == 1) ? Wk : Wv;
  f32x4 acc[4][4];
  gemm_wave64(x, W, 1024, m0, n0, acc);

  const int lane = threadIdx.x & 63;
  const int lr = lane & 15, lg = lane >> 4;
  bf16* out = (mode == 0) ? q_ws : (mode == 1) ? k_ws : vt_ws;
#pragma unroll
  for (int i = 0; i < 4; ++i) {
#pragma unroll
    for (int r = 0; r < 4; ++r) {
      const int m = m0 + i * 16 + lg * 4 + r;        // C/D: row = quad*4 + reg
      const int b = m >> 11, t = m & 2047;
#pragma unroll
      for (int j = 0; j < 4; ++j) {
        const int n = n0 + j * 16 + lr;              // C/D: col = lane&15
        const int h = n >> 6, d = n & 63;
        const float v = acc[i][j][r];
        const size_t base = ((size_t)(b * 16 + h) << 17) + ((size_t)(t >> 6) << 12);
        const size_t idx = base + ((mode < 2) ? frag_idx(t & 63, d) : frag_idx(d, t & 63));
        out[idx] = (bf16)v;
      }
    }
  }
}

// Flash attention v4: balanced + pipelined + XCD-colocated (unchanged).
__global__ __launch_bounds__(256, 2) void attn_kernel(
    const bf16* __restrict__ q_ws, const bf16* __restrict__ k_ws,
    const bf16* __restrict__ vt_ws, bf16* __restrict__ a_ws) {
  const int L = blockIdx.x;
  const int xcd = L & 7;
  const int bh = xcd * 4 + ((L >> 3) & 3);      // b*16 + h
  const int pr = L >> 5;                        // 0..15
  const int tid = threadIdx.x;
  const int lane = tid & 63, w = tid >> 6;
  const int lr = lane & 15, lg = lane >> 4;
  const int fo = lg * 16 + lr;                  // lane's chunk-in-run index

  __shared__ alignas(16) bf16 Ps[4][16 * 72];   // per-wave P strip, pad 72
  bf16* ps = &Ps[w][0];

  const size_t hb = (size_t)bh << 17;
  const int b = bh >> 4, h = bh & 15;
  const f32x4 zero = {0.f, 0.f, 0.f, 0.f};

  for (int ph = 0; ph < 2; ++ph) {
    const int qt = ph ? (31 - pr) : pr;
    const size_t qtb = hb + ((size_t)qt << 12);

    bf16x8 aq[2];
#pragma unroll
    for (int c2 = 0; c2 < 2; ++c2)
      aq[c2] = load8(q_ws + qtb + (size_t)(((c2 * 4 + w) * 64 + fo) << 3));

    f32x4 o_acc[4];
#pragma unroll
    for (int j = 0; j < 4; ++j) o_acc[j] = zero;
    float lsum[4] = {0.f, 0.f, 0.f, 0.f};

    auto load_k = [&](bf16x8 (&bk)[4][2], int kt) {
      const size_t ktb = hb + ((size_t)kt << 12);
#pragma unroll
      for (int j = 0; j < 4; ++j)
#pragma unroll
        for (int c2 = 0; c2 < 2; ++c2)
          bk[j][c2] = load8(k_ws + ktb + (size_t)(((c2 * 4 + j) * 64 + fo) << 3));
    };

    auto step = [&](const bf16x8 (&bk)[4][2], int kt, bool diag) {
      const size_t ktb = hb + ((size_t)kt << 12);
      bf16x8 bv[4][2];
#pragma unroll
      for (int j = 0; j < 4; ++j)
#pragma unroll
        for (int c2 = 0; c2 < 2; ++c2)
          bv[j][c2] = load8(vt_ws + ktb + (size_t)(((c2 * 4 + j) * 64 + fo) << 3));

      f32x4 s[4];
#pragma unroll
      for (int j = 0; j < 4; ++j) {
        s[j] = __builtin_amdgcn_mfma_f32_16x16x32_bf16(aq[0], bk[j][0], zero, 0, 0, 0);
        s[j] = __builtin_amdgcn_mfma_f32_16x16x32_bf16(aq[1], bk[j][1], s[j], 0, 0, 0);
      }
      float p[4][4];
#pragma unroll
      for (int j = 0; j < 4; ++j) {
#pragma unroll
        for (int r = 0; r < 4; ++r) {
          float v = s[j][r] * 0.125f;
          if (diag && (j * 16 + lr) > (w * 16 + lg * 4 + r)) v = NEG_BIG;
          p[j][r] = __expf(v);             // exp(-1e30) flushes to 0
        }
      }
#pragma unroll
      for (int r = 0; r < 4; ++r)
        lsum[r] += (p[0][r] + p[1][r]) + (p[2][r] + p[3][r]);
#pragma unroll
      for (int j = 0; j < 4; ++j)
#pragma unroll
        for (int r = 0; r < 4; ++r)
          ps[(lg * 4 + r) * 72 + j * 16 + lr] = (bf16)p[j][r];
#pragma unroll
      for (int c2 = 0; c2 < 2; ++c2) {
        const bf16x8 ap = load8(ps + lr * 72 + c2 * 32 + lg * 8);
#pragma unroll
        for (int j = 0; j < 4; ++j)
          o_acc[j] = __builtin_amdgcn_mfma_f32_16x16x32_bf16(ap, bv[j][c2], o_acc[j], 0, 0, 0);
      }
    };

    bf16x8 bkA[4][2], bkB[4][2];
    const int n = qt;
    load_k(bkA, qt);
    if (n > 0) load_k(bkB, 0);
    step(bkA, qt, true);
    int kt = 0;
    while (kt + 1 < n) {
      load_k(bkA, kt + 1);
      step(bkB, kt, false);
      if (kt + 2 < n) load_k(bkB, kt + 2);
      step(bkA, kt + 1, false);
      kt += 2;
    }
    if (kt < n) step(bkB, kt, false);

    float l_i[4];
#pragma unroll
    for (int r = 0; r < 4; ++r) {
      float v = lsum[r];
#pragma unroll
      for (int off = 1; off < 16; off <<= 1) v += __shfl_xor(v, off, 64);
      l_i[r] = v;
    }

#pragma unroll
    for (int r = 0; r < 4; ++r) {
      const int t = qt * 64 + w * 16 + lg * 4 + r;
      const float inv = 1.f / l_i[r];
#pragma unroll
      for (int j = 0; j < 4; ++j) {
        const size_t idx = (((size_t)(b * 2048 + t)) << 10) | (size_t)(h * 64 + j * 16 + lr);
        a_ws[idx] = (bf16)(o_acc[j][r] * inv);
      }
    }
  }
}

// 1-D grid 1024 single-wave blocks. Per XCD: 8 m-tiles (1 MiB A-slice) x 16 n
// -> A-slice + Wp (2 MiB) L2-resident per XCD.
__global__ __launch_bounds__(64) void out_proj_kernel(
    const bf16* __restrict__ A, const bf16* __restrict__ Wp,
    const bf16* __restrict__ bp, void* __restrict__ out,
    const unsigned short* __restrict__ xraw) {
  const int L = blockIdx.x;
  const int xcd = L & 7;
  const int i2 = L >> 3;                 // 0..127
  const int m0 = (xcd * 8 + (i2 & 7)) << 6;
  const int n0 = (i2 >> 3) << 6;
  f32x4 acc[4][4];
  gemm_wave64(A, Wp, 1024, m0, n0, acc);

  const int lane = threadIdx.x & 63;
  const int lr = lane & 15, lg = lane >> 4;
  const int isbf = sniff_bf16(xraw);     // output dtype == input dtype
#pragma unroll
  for (int i = 0; i < 4; ++i) {
#pragma unroll
    for (int r = 0; r < 4; ++r) {
      const int m = m0 + i * 16 + lg * 4 + r;
#pragma unroll
      for (int j = 0; j < 4; ++j) {
        const int n = n0 + j * 16 + lr;
        const float v = acc[i][j][r] + (float)bp[n];
        const size_t idx = ((size_t)m << 10) | (size_t)n;
        if (isbf) ((bf16*)out)[idx] = (bf16)v;
        else      ((float*)out)[idx] = v;
      }
    }
  }
}

extern "C" void kernel_launch(void* const* d_in, const int* in_sizes, int n_in,
                              void* d_out, int out_size, void* d_ws, size_t ws_size,
                              hipStream_t stream) {
  (void)in_sizes; (void)n_in; (void)out_size;
  if (ws_size < (50u << 20)) return;   // tripwire (round-4: ws is big enough)

  char* ws = (char*)d_ws;
  bf16* q_ws  = (bf16*)(ws);                        // 8 MiB frag-order Q
  bf16* k_ws  = (bf16*)(ws + (8u << 20));           // 8 MiB frag-order K
  bf16* vt_ws = (bf16*)(ws + (16u << 20));          // 8 MiB frag-order V^T
  bf16* a_ws  = (bf16*)(ws + (24u << 20));          // 8 MiB row-major attn out
  bf16* xc    = (bf16*)(ws + (32u << 20));          // 8 MiB canonical x
  bf16* Wqc   = (bf16*)(ws + (40u << 20));          // 2 MiB each
  bf16* Wkc   = (bf16*)(ws + (42u << 20));
  bf16* Wvc   = (bf16*)(ws + (44u << 20));
  bf16* Wpc   = (bf16*)(ws + (46u << 20));
  bf16* bpc   = (bf16*)(ws + (48u << 20));

  ConvArgs ca;
  ca.src[0] = d_in[0]; ca.dst[0] = xc;  ca.n[0] = 4096 * 1024;
  ca.src[1] = d_in[1]; ca.dst[1] = Wqc; ca.n[1] = 1024 * 1024;
  ca.src[2] = d_in[2]; ca.dst[2] = Wkc; ca.n[2] = 1024 * 1024;
  ca.src[3] = d_in[3]; ca.dst[3] = Wvc; ca.n[3] = 1024 * 1024;
  ca.src[4] = d_in[4]; ca.dst[4] = Wpc; ca.n[4] = 1024 * 1024;
  ca.src[5] = d_in[5]; ca.dst[5] = bpc; ca.n[5] = 1024;
  convert_kernel<<<dim3(512, 6), 256, 0, stream>>>(ca);

  qkv_proj_kernel<<<3072, 64, 0, stream>>>(xc, Wqc, Wkc, Wvc, q_ws, k_ws, vt_ws);
  attn_kernel<<<512, 256, 0, stream>>>(q_ws, k_ws, vt_ws, a_ws);
  out_proj_kernel<<<1024, 64, 0, stream>>>(a_ws, Wpc, bpc, d_out,
                                           (const unsigned short*)d_in[0]);
}

// Round 3
// 178.329 us; speedup vs baseline: 1.4941x; 1.4941x over previous
//
#include <hip/hip_runtime.h>

typedef __bf16 bf16;
typedef __bf16 bf16x8 __attribute__((ext_vector_type(8)));
typedef float f32x4 __attribute__((ext_vector_type(4)));

typedef __attribute__((address_space(1))) const void as1_void;
typedef __attribute__((address_space(3))) void as3_void;

#define DEV __device__ __forceinline__
#define NEG_BIG (-1.0e30f)

// B=2, T=2048, C=1024, H=16, D=64; M = B*T = 4096

DEV void async_load16(const void* g, void* l) {
  __builtin_amdgcn_global_load_lds((as1_void*)g, (as3_void*)l, 16, 0, 0);
}
DEV bf16x8 load8(const bf16* p) { bf16x8 v; __builtin_memcpy(&v, p, 16); return v; }
DEV void store8(bf16* p, bf16x8 v) { __builtin_memcpy(p, &v, 16); }

// ---------------- in-kernel dtype sniff (block-uniform, deterministic) ----------------
DEV int sniff_bf16(const unsigned short* __restrict__ xr) {
  const int lane = threadIdx.x & 63;
  const unsigned short w = xr[lane * 2];
  const int e = (w >> 7) & 0xFF;
  const bool sane = ((w & 0x7FFF) == 0) || (e >= 97 && e <= 157);
  return __popcll(__ballot(sane)) >= 48;
}

// ---------------- input canonicalization (-> bf16, row-major) ----------------
struct ConvArgs {
  const void* src[6];
  bf16* dst[6];
  int n[6];
};

__global__ __launch_bounds__(256) void convert_kernel(ConvArgs a) {
  const int isbf = sniff_bf16((const unsigned short*)a.src[0]);
  const int t = blockIdx.y;
  const int n = a.n[t];
  bf16* d = a.dst[t];
  const int stride = gridDim.x * 256 * 8;
  if (isbf) {
    const bf16* s = (const bf16*)a.src[t];
    for (int i = (blockIdx.x * 256 + threadIdx.x) * 8; i < n; i += stride)
      store8(d + i, load8(s + i));
  } else {
    const float* s = (const float*)a.src[t];
    for (int i = (blockIdx.x * 256 + threadIdx.x) * 8; i < n; i += stride) {
      float tmp[8];
      __builtin_memcpy(tmp, s + i, 32);
      bf16x8 v;
#pragma unroll
      for (int j = 0; j < 8; ++j) v[j] = (bf16)tmp[j];
      store8(d + i, v);
    }
  }
}

// ---------------- GEMM core v3: BK=32, 3 LDS buffers, 1 barrier/K-tile ----------------
// acc[4][4] = A[m0:m0+128, :] * W[n0:n0+128, :]^T; 4 waves (2x2), 48 KiB LDS
// -> 3 blocks/CU. Counted vmcnt(4) (tile t+1 stays in flight), prefetch
// distance 1 K-tile (~900cy of compute between issue and use), and a single
// barrier per K-tile: buffer written at iter t was last READ at iter t-1,
// and every wave passing barrier(t) has already consumed (not just issued)
// its tile-(t-1) ds_reads, so the re-write cannot race.
// LDS layout (per 128x32 tile): lds-row pair r2 = row>>1 holds 8 16B chunks;
// chunk c stores k-group g, row-parity b2 with (g | b2<<2) = c ^ (r2 & 7).
// Fragment read for (row, g=lane>>4) hits bank group 4*((g|(row&1)<<2)^(r2&7));
// each 16-lane group covers all 8 bank groups exactly twice -> 2-way = free.
DEV void gemm_core_128_p(const bf16* A, const bf16* W, const int K, int m0, int n0,
                         f32x4 (&acc)[4][4]) {
  __shared__ alignas(16) bf16 As[3][128 * 32];
  __shared__ alignas(16) bf16 Bs[3][128 * 32];
  const int tid = threadIdx.x;
  const int lane = tid & 63;
  const int wid = tid >> 6;
  const int wm = (wid >> 1) << 6;
  const int wn = (wid & 1) << 6;
  const int lr = lane & 15;
  const int lg = lane >> 4;

  // per-thread loop-invariant staging offsets (2 chunks per matrix per tile)
  size_t srcA[2], srcB[2];
  int ldsoff[2];
#pragma unroll
  for (int it = 0; it < 2; ++it) {
    const int lin = it * 256 + tid;        // 16B chunk id, 0..511
    const int lr2 = lin >> 3, c = lin & 7;
    const int u = c ^ (lr2 & 7);
    const int r = lr2 * 2 + (u >> 2);      // source row 0..127
    const int g = u & 3;                   // source k-group (8 elems)
    srcA[it] = (size_t)(m0 + r) * K + (size_t)(g * 8);
    srcB[it] = (size_t)(n0 + r) * K + (size_t)(g * 8);
    ldsoff[it] = lin * 8;
  }
  // per-thread loop-invariant fragment read offsets
  int offA[4], offB[4];
#pragma unroll
  for (int i = 0; i < 4; ++i) {
    const int r = wm + i * 16 + lr;
    const int cc = (lg | ((r & 1) << 2)) ^ ((r >> 1) & 7);
    offA[i] = (((r >> 1) << 3) | cc) * 8;
  }
#pragma unroll
  for (int j = 0; j < 4; ++j) {
    const int r = wn + j * 16 + lr;
    const int cc = (lg | ((r & 1) << 2)) ^ ((r >> 1) & 7);
    offB[j] = (((r >> 1) << 3) | cc) * 8;
  }

  const f32x4 zero = {0.f, 0.f, 0.f, 0.f};
#pragma unroll
  for (int i = 0; i < 4; ++i)
#pragma unroll
    for (int j = 0; j < 4; ++j) acc[i][j] = zero;

  const int nt = K >> 5;  // 32

  auto stage = [&](int buf, int t) {
    const size_t k0 = (size_t)(t << 5);
#pragma unroll
    for (int it = 0; it < 2; ++it) {
      async_load16(A + srcA[it] + k0, &As[buf][0] + ldsoff[it]);
      async_load16(W + srcB[it] + k0, &Bs[buf][0] + ldsoff[it]);
    }
  };

  auto compute = [&](int buf) {
    const bf16* as = &As[buf][0];
    const bf16* bs = &Bs[buf][0];
    bf16x8 af[4], bfr[4];
#pragma unroll
    for (int i = 0; i < 4; ++i) af[i] = load8(as + offA[i]);
#pragma unroll
    for (int j = 0; j < 4; ++j) bfr[j] = load8(bs + offB[j]);
    __builtin_amdgcn_s_setprio(1);
#pragma unroll
    for (int i = 0; i < 4; ++i)
#pragma unroll
      for (int j = 0; j < 4; ++j)
        acc[i][j] = __builtin_amdgcn_mfma_f32_16x16x32_bf16(af[i], bfr[j], acc[i][j], 0, 0, 0);
    __builtin_amdgcn_s_setprio(0);
  };

  // prologue: tiles 0 and 1 in flight
  stage(0, 0);
  stage(1, 1);
  int b0 = 0, b1 = 1, b2 = 2;
  for (int t = 0; t < nt; ++t) {
    // tile t must have landed; tile t+1 (4 loads/thread) stays in flight
    if (t + 1 < nt) asm volatile("s_waitcnt vmcnt(4)" ::: "memory");
    else            asm volatile("s_waitcnt vmcnt(0)" ::: "memory");
    __builtin_amdgcn_s_barrier();          // all waves' tile-t portions in LDS
    if (t + 2 < nt) stage(b2, t + 2);      // buffer last read at iter t-1: safe
    compute(b0);
    const int tmp = b0; b0 = b1; b1 = b2; b2 = tmp;
  }
}

// ---------------- GEMM core (r1): BK=64, 2 buffers, 2-deep, 2 barriers -------------
DEV void gemm_core_128(const bf16* A, const bf16* W, int K, int m0, int n0,
                       f32x4 (&acc)[4][4]) {
  __shared__ alignas(16) bf16 As[2][128 * 64];
  __shared__ alignas(16) bf16 Bs[2][128 * 64];
  const int tid = threadIdx.x;
  const int lane = tid & 63;
  const int wid = tid >> 6;
  const int wm = (wid >> 1) << 6;
  const int wn = (wid & 1) << 6;
  const int lr = lane & 15;
  const int lg = lane >> 4;

  const f32x4 zero = {0.f, 0.f, 0.f, 0.f};
#pragma unroll
  for (int i = 0; i < 4; ++i)
#pragma unroll
    for (int j = 0; j < 4; ++j) acc[i][j] = zero;

  const int nt = K >> 6;  // 16

  auto stage = [&](int buf, int t) {
    const int k0 = t << 6;
#pragma unroll
    for (int it = 0; it < 4; ++it) {
      const int lin = it * 256 + tid;        // 16B chunk id
      const int row = lin >> 3;              // 0..127
      const int sc = (lin & 7) ^ (row & 7);  // swizzled source k-group
      async_load16(A + (size_t)(m0 + row) * K + (size_t)(k0 + sc * 8),
                   &As[buf][0] + lin * 8);
      async_load16(W + (size_t)(n0 + row) * K + (size_t)(k0 + sc * 8),
                   &Bs[buf][0] + lin * 8);
    }
  };

  auto compute = [&](int buf) {
    const bf16* as = &As[buf][0];
    const bf16* bs = &Bs[buf][0];
#pragma unroll
    for (int kk = 0; kk < 64; kk += 32) {
      const int g0 = kk >> 3;
      bf16x8 af[4], bfr[4];
#pragma unroll
      for (int i = 0; i < 4; ++i) {
        const int r = wm + i * 16 + lr;
        af[i] = load8(as + ((r << 3) | ((g0 + lg) ^ (r & 7))) * 8);
      }
#pragma unroll
      for (int j = 0; j < 4; ++j) {
        const int r = wn + j * 16 + lr;
        bfr[j] = load8(bs + ((r << 3) | ((g0 + lg) ^ (r & 7))) * 8);
      }
#pragma unroll
      for (int i = 0; i < 4; ++i)
#pragma unroll
        for (int j = 0; j < 4; ++j)
          acc[i][j] = __builtin_amdgcn_mfma_f32_16x16x32_bf16(af[i], bfr[j], acc[i][j], 0, 0, 0);
    }
  };

  stage(0, 0);
  stage(1, 1);
  int cur = 0;
  for (int t = 0; t < nt; ++t) {
    if (t + 1 < nt) asm volatile("s_waitcnt vmcnt(8)" ::: "memory");
    else            asm volatile("s_waitcnt vmcnt(0)" ::: "memory");
    __builtin_amdgcn_s_barrier();          // all waves' tile-t portions in LDS
    compute(cur);
    asm volatile("s_waitcnt lgkmcnt(0)" ::: "memory");  // our tile-t reads done
    __builtin_amdgcn_s_barrier();          // all waves done reading tile t
    if (t + 2 < nt) stage(cur, t + 2);     // overwrite consumed buffer
    cur ^= 1;
  }
}

// Fragment-order address for a 64x64 tile, element (row, col):
//   chunk = ((col>>5)*4 + ((row>>4)&3))*64 + ((col>>3)&3)*16 + (row&15), elem = col&7
// Q/K use (row=t-in-tile, col=d); V^T uses (row=d, col=t-in-tile).
DEV size_t frag_idx(int row, int col) {
  return ((size_t)(((col >> 5) * 4 + ((row >> 4) & 3)) * 64 + ((col >> 3) & 3) * 16 + (row & 15)) << 3)
         | (size_t)(col & 7);
}

// 1-D grid 768. xcd = L&7, 4 m0-tiles colocated per XCD; rest = (n0, mode).
__global__ __launch_bounds__(256) void qkv_proj_kernel(
    const bf16* __restrict__ x, const bf16* __restrict__ Wq,
    const bf16* __restrict__ Wk, const bf16* __restrict__ Wv,
    bf16* __restrict__ q_ws, bf16* __restrict__ k_ws, bf16* __restrict__ vt_ws) {
  const int L = blockIdx.x;
  const int xcd = L & 7;
  const int i2 = L >> 3;                 // 0..95
  const int m0 = (xcd * 4 + (i2 & 3)) << 7;
  const int rest = i2 >> 2;              // 0..23
  const int n0 = (rest & 7) << 7;
  const int mode = rest >> 3;            // 0..2
  const bf16* W = (mode == 0) ? Wq : (mode == 1) ? Wk : Wv;
  f32x4 acc[4][4];
  gemm_core_128_p(x, W, 1024, m0, n0, acc);

  const int tid = threadIdx.x;
  const int lane = tid & 63, wid = tid >> 6;
  const int wm = (wid >> 1) << 6, wn = (wid & 1) << 6;
  const int lr = lane & 15, lg = lane >> 4;
  bf16* out = (mode == 0) ? q_ws : (mode == 1) ? k_ws : vt_ws;
#pragma unroll
  for (int i = 0; i < 4; ++i) {
#pragma unroll
    for (int r = 0; r < 4; ++r) {
      const int m = m0 + wm + i * 16 + lg * 4 + r;   // C/D: row = quad*4 + reg
      const int b = m >> 11, t = m & 2047;
#pragma unroll
      for (int j = 0; j < 4; ++j) {
        const int n = n0 + wn + j * 16 + lr;          // C/D: col = lane&15
        const int h = n >> 6, d = n & 63;
        const float v = acc[i][j][r];
        const size_t base = ((size_t)(b * 16 + h) << 17) + ((size_t)(t >> 6) << 12);
        const size_t idx = base + ((mode < 2) ? frag_idx(t & 63, d) : frag_idx(d, t & 63));
        out[idx] = (bf16)v;
      }
    }
  }
}

// Flash attention v4: balanced + pipelined + XCD-colocated (unchanged).
__global__ __launch_bounds__(256, 2) void attn_kernel(
    const bf16* __restrict__ q_ws, const bf16* __restrict__ k_ws,
    const bf16* __restrict__ vt_ws, bf16* __restrict__ a_ws) {
  const int L = blockIdx.x;
  const int xcd = L & 7;
  const int bh = xcd * 4 + ((L >> 3) & 3);      // b*16 + h
  const int pr = L >> 5;                        // 0..15
  const int tid = threadIdx.x;
  const int lane = tid & 63, w = tid >> 6;
  const int lr = lane & 15, lg = lane >> 4;
  const int fo = lg * 16 + lr;                  // lane's chunk-in-run index

  __shared__ alignas(16) bf16 Ps[4][16 * 72];   // per-wave P strip, pad 72
  bf16* ps = &Ps[w][0];

  const size_t hb = (size_t)bh << 17;
  const int b = bh >> 4, h = bh & 15;
  const f32x4 zero = {0.f, 0.f, 0.f, 0.f};

  for (int ph = 0; ph < 2; ++ph) {
    const int qt = ph ? (31 - pr) : pr;
    const size_t qtb = hb + ((size_t)qt << 12);

    bf16x8 aq[2];
#pragma unroll
    for (int c2 = 0; c2 < 2; ++c2)
      aq[c2] = load8(q_ws + qtb + (size_t)(((c2 * 4 + w) * 64 + fo) << 3));

    f32x4 o_acc[4];
#pragma unroll
    for (int j = 0; j < 4; ++j) o_acc[j] = zero;
    float lsum[4] = {0.f, 0.f, 0.f, 0.f};

    auto load_k = [&](bf16x8 (&bk)[4][2], int kt) {
      const size_t ktb = hb + ((size_t)kt << 12);
#pragma unroll
      for (int j = 0; j < 4; ++j)
#pragma unroll
        for (int c2 = 0; c2 < 2; ++c2)
          bk[j][c2] = load8(k_ws + ktb + (size_t)(((c2 * 4 + j) * 64 + fo) << 3));
    };

    auto step = [&](const bf16x8 (&bk)[4][2], int kt, bool diag) {
      const size_t ktb = hb + ((size_t)kt << 12);
      bf16x8 bv[4][2];
#pragma unroll
      for (int j = 0; j < 4; ++j)
#pragma unroll
        for (int c2 = 0; c2 < 2; ++c2)
          bv[j][c2] = load8(vt_ws + ktb + (size_t)(((c2 * 4 + j) * 64 + fo) << 3));

      f32x4 s[4];
#pragma unroll
      for (int j = 0; j < 4; ++j) {
        s[j] = __builtin_amdgcn_mfma_f32_16x16x32_bf16(aq[0], bk[j][0], zero, 0, 0, 0);
        s[j] = __builtin_amdgcn_mfma_f32_16x16x32_bf16(aq[1], bk[j][1], s[j], 0, 0, 0);
      }
      float p[4][4];
#pragma unroll
      for (int j = 0; j < 4; ++j) {
#pragma unroll
        for (int r = 0; r < 4; ++r) {
          float v = s[j][r] * 0.125f;
          if (diag && (j * 16 + lr) > (w * 16 + lg * 4 + r)) v = NEG_BIG;
          p[j][r] = __expf(v);             // exp(-1e30) flushes to 0
        }
      }
#pragma unroll
      for (int r = 0; r < 4; ++r)
        lsum[r] += (p[0][r] + p[1][r]) + (p[2][r] + p[3][r]);
#pragma unroll
      for (int j = 0; j < 4; ++j)
#pragma unroll
        for (int r = 0; r < 4; ++r)
          ps[(lg * 4 + r) * 72 + j * 16 + lr] = (bf16)p[j][r];
#pragma unroll
      for (int c2 = 0; c2 < 2; ++c2) {
        const bf16x8 ap = load8(ps + lr * 72 + c2 * 32 + lg * 8);
#pragma unroll
        for (int j = 0; j < 4; ++j)
          o_acc[j] = __builtin_amdgcn_mfma_f32_16x16x32_bf16(ap, bv[j][c2], o_acc[j], 0, 0, 0);
      }
    };

    bf16x8 bkA[4][2], bkB[4][2];
    const int n = qt;
    load_k(bkA, qt);
    if (n > 0) load_k(bkB, 0);
    step(bkA, qt, true);
    int kt = 0;
    while (kt + 1 < n) {
      load_k(bkA, kt + 1);
      step(bkB, kt, false);
      if (kt + 2 < n) load_k(bkB, kt + 2);
      step(bkA, kt + 1, false);
      kt += 2;
    }
    if (kt < n) step(bkB, kt, false);

    float l_i[4];
#pragma unroll
    for (int r = 0; r < 4; ++r) {
      float v = lsum[r];
#pragma unroll
      for (int off = 1; off < 16; off <<= 1) v += __shfl_xor(v, off, 64);
      l_i[r] = v;
    }

#pragma unroll
    for (int r = 0; r < 4; ++r) {
      const int t = qt * 64 + w * 16 + lg * 4 + r;
      const float inv = 1.f / l_i[r];
#pragma unroll
      for (int j = 0; j < 4; ++j) {
        const size_t idx = (((size_t)(b * 2048 + t)) << 10) | (size_t)(h * 64 + j * 16 + lr);
        a_ws[idx] = (bf16)(o_acc[j][r] * inv);
      }
    }
  }
}

// 1-D grid 256: 4 m-tiles colocated per XCD -> A + Wp L2-resident per XCD.
__global__ __launch_bounds__(256) void out_proj_kernel(
    const bf16* __restrict__ A, const bf16* __restrict__ Wp,
    const bf16* __restrict__ bp, void* __restrict__ out,
    const unsigned short* __restrict__ xraw) {
  const int L = blockIdx.x;
  const int xcd = L & 7;
  const int i2 = L >> 3;                 // 0..31
  const int m0 = (xcd * 4 + (i2 & 3)) << 7;
  const int n0 = (i2 >> 2) << 7;
  f32x4 acc[4][4];
  gemm_core_128(A, Wp, 1024, m0, n0, acc);

  const int tid = threadIdx.x;
  const int lane = tid & 63, wid = tid >> 6;
  const int wm = (wid >> 1) << 6, wn = (wid & 1) << 6;
  const int lr = lane & 15, lg = lane >> 4;
  const int isbf = sniff_bf16(xraw);     // output dtype == input dtype
#pragma unroll
  for (int i = 0; i < 4; ++i) {
#pragma unroll
    for (int r = 0; r < 4; ++r) {
      const int m = m0 + wm + i * 16 + lg * 4 + r;
#pragma unroll
      for (int j = 0; j < 4; ++j) {
        const int n = n0 + wn + j * 16 + lr;
        const float v = acc[i][j][r] + (float)bp[n];
        const size_t idx = ((size_t)m << 10) | (size_t)n;
        if (isbf) ((bf16*)out)[idx] = (bf16)v;
        else      ((float*)out)[idx] = v;
      }
    }
  }
}

extern "C" void kernel_launch(void* const* d_in, const int* in_sizes, int n_in,
                              void* d_out, int out_size, void* d_ws, size_t ws_size,
                              hipStream_t stream) {
  (void)in_sizes; (void)n_in; (void)out_size;
  if (ws_size < (50u << 20)) return;   // tripwire (round-4: ws is big enough)

  char* ws = (char*)d_ws;
  bf16* q_ws  = (bf16*)(ws);                        // 8 MiB frag-order Q
  bf16* k_ws  = (bf16*)(ws + (8u << 20));           // 8 MiB frag-order K
  bf16* vt_ws = (bf16*)(ws + (16u << 20));          // 8 MiB frag-order V^T
  bf16* a_ws  = (bf16*)(ws + (24u << 20));          // 8 MiB row-major attn out
  bf16* xc    = (bf16*)(ws + (32u << 20));          // 8 MiB canonical x
  bf16* Wqc   = (bf16*)(ws + (40u << 20));          // 2 MiB each
  bf16* Wkc   = (bf16*)(ws + (42u << 20));
  bf16* Wvc   = (bf16*)(ws + (44u << 20));
  bf16* Wpc   = (bf16*)(ws + (46u << 20));
  bf16* bpc   = (bf16*)(ws + (48u << 20));

  ConvArgs ca;
  ca.src[0] = d_in[0]; ca.dst[0] = xc;  ca.n[0] = 4096 * 1024;
  ca.src[1] = d_in[1]; ca.dst[1] = Wqc; ca.n[1] = 1024 * 1024;
  ca.src[2] = d_in[2]; ca.dst[2] = Wkc; ca.n[2] = 1024 * 1024;
  ca.src[3] = d_in[3]; ca.dst[3] = Wvc; ca.n[3] = 1024 * 1024;
  ca.src[4] = d_in[4]; ca.dst[4] = Wpc; ca.n[4] = 1024 * 1024;
  ca.src[5] = d_in[5]; ca.dst[5] = bpc; ca.n[5] = 1024;
  convert_kernel<<<dim3(512, 6), 256, 0, stream>>>(ca);

  qkv_proj_kernel<<<768, 256, 0, stream>>>(xc, Wqc, Wkc, Wvc, q_ws, k_ws, vt_ws);
  attn_kernel<<<512, 256, 0, stream>>>(q_ws, k_ws, vt_ws, a_ws);
  out_proj_kernel<<<256, 256, 0, stream>>>(a_ws, Wpc, bpc, d_out,
                                           (const unsigned short*)d_in[0]);
}